// Round 14
// baseline (611.965 us; speedup 1.0000x reference)
//
#include <hip/hip_runtime.h>
#include <math.h>

// LightingSpeechShield — B=1024, F=257, C=32; fp32 in/out.
// R13: 600 µs (k_layer 86 µs VALU-issue-bound; conv stored once, read back).
// R14: packed fp32 math — float2 ext-vector + __builtin_elementwise_fma
//      lowers to v_pk_fma_f32 (CDNA VOP3P): every dot4 = 2 pk-FMA instead of
//      4 v_fma. Applied to k_conv window, k_layer qkv/proj, k_head. All packed
//      values are NAMED v2f scalars (no arrays — R8/R9 scratch lesson).

#define BB 1024
#define FF 257
#define BF (BB*FF)
#define TILE 64
#define NT 5
#define NBLK (BB*NT)       // 5120
#define NLAYER 4
#define SQ 36              // qs/ks/vs row stride (16B-aligned)

typedef float v2f __attribute__((ext_vector_type(2)));
__device__ __forceinline__ v2f mk2(float a, float b){ v2f r; r.x=a; r.y=b; return r; }
__device__ __forceinline__ v2f pkfma(v2f a, v2f b, v2f c){ return __builtin_elementwise_fma(a,b,c); }
__device__ __forceinline__ float hadd(v2f a){ return a.x+a.y; }
__device__ __forceinline__ float gelu_exact(float x){
    return 0.5f*x*(1.0f+erff(x*0.70710678118654752f));
}
__device__ __forceinline__ float dot4(float4 a, float4 b, float acc){
    return fmaf(a.x,b.x,fmaf(a.y,b.y,fmaf(a.z,b.z,fmaf(a.w,b.w,acc))));
}

__global__ __launch_bounds__(256) void k_zero(float* __restrict__ stats){
    stats[threadIdx.x]=0.0f;   // 256 = NLAYER*64
}

// ---------------- input projection: h = x(B,F,18) @ in_w(18,32) + in_b ----------------
__global__ __launch_bounds__(256) void k_inproj(const float* __restrict__ x,
        const float* __restrict__ in_w, const float* __restrict__ in_b,
        float* __restrict__ h)
{
    __shared__ float xs[TILE*18];
    int b = blockIdx.x / NT, t = blockIdx.x % NT, t0 = t*TILE;
    int tid = threadIdx.x;
    int nv = min(TILE, FF-t0);
    for (int i=tid;i<nv*18;i+=256) xs[i]=x[(size_t)(b*FF+t0)*18+i];
    __syncthreads();
    int co=tid&31, rq=tid>>5, rbase=rq*8;
    float bias = in_b[co];
    float a0=bias,a1=bias,a2=bias,a3=bias,a4=bias,a5=bias,a6=bias,a7=bias;
    #pragma unroll
    for (int ci=0;ci<18;ci++){
        float w = in_w[ci*32+co];
        a0=fmaf(xs[(rbase+0)*18+ci],w,a0);
        a1=fmaf(xs[(rbase+1)*18+ci],w,a1);
        a2=fmaf(xs[(rbase+2)*18+ci],w,a2);
        a3=fmaf(xs[(rbase+3)*18+ci],w,a3);
        a4=fmaf(xs[(rbase+4)*18+ci],w,a4);
        a5=fmaf(xs[(rbase+5)*18+ci],w,a5);
        a6=fmaf(xs[(rbase+6)*18+ci],w,a6);
        a7=fmaf(xs[(rbase+7)*18+ci],w,a7);
    }
    size_t base=(size_t)(b*FF+t0+rbase)*32+co;
    if (rbase+0<nv) h[base+0*32]=a0;
    if (rbase+1<nv) h[base+1*32]=a1;
    if (rbase+2<nv) h[base+2*32]=a2;
    if (rbase+3<nv) h[base+3*32]=a3;
    if (rbase+4<nv) h[base+4*32]=a4;
    if (rbase+5<nv) h[base+5*32]=a5;
    if (rbase+6<nv) h[base+6*32]=a6;
    if (rbase+7<nv) h[base+7*32]=a7;
}

#define ROWLOAD(HR) { float4 t_=*(const float4*)(HR); hp=mk2(t_.x,t_.y); hq=mk2(t_.z,t_.w); }
#define TAP(A,WA,WB) A=pkfma(hp,WA,A); A=pkfma(hq,WB,A);

// ---------------- conv -> store raw conv to `c` + BN partial sums ----------------
__global__ __launch_bounds__(256) void k_conv(const float* __restrict__ h,
        const float* __restrict__ conv_w, int layer, float* __restrict__ c,
        float* __restrict__ partials)
{
    __shared__ float hs[66*32];      // rows f = t0-1 .. t0+64
    __shared__ float ps[8][32];
    __shared__ float pq[8][32];
    int b=blockIdx.x/NT, t=blockIdx.x%NT, t0=t*TILE, tid=threadIdx.x;
    for (int i4=tid;i4<66*8;i4+=256){
        int r=i4>>3, f=t0-1+r;
        float4 v=make_float4(0.f,0.f,0.f,0.f);
        if (f>=0 && f<FF) v=*(const float4*)(h+(size_t)(b*FF+f)*32+(i4&7)*4);
        *(float4*)&hs[r*32+(i4&7)*4]=v;
    }
    __syncthreads();
    int co=tid&31, rq=tid>>5, rbase=rq*8;
    const float* wl = conv_w + layer*3072 + co;   // [wi][ci][co]
    v2f a0=mk2(0,0),a1=a0,a2=a0,a3=a0,a4=a0,a5=a0,a6=a0,a7=a0;
    v2f hp, hq;
    #pragma unroll 1
    for (int c4=0;c4<8;c4++){
        const float* w=wl+c4*128;
        v2f w0a=mk2(w[0],   w[32]),  w0b=mk2(w[64],  w[96]);
        v2f w1a=mk2(w[1024],w[1056]),w1b=mk2(w[1088],w[1120]);
        v2f w2a=mk2(w[2048],w[2080]),w2b=mk2(w[2112],w[2144]);
        const float* hb=&hs[rbase*32+c4*4];
        ROWLOAD(hb+0*32) TAP(a0,w0a,w0b)
        ROWLOAD(hb+1*32) TAP(a0,w1a,w1b) TAP(a1,w0a,w0b)
        ROWLOAD(hb+2*32) TAP(a0,w2a,w2b) TAP(a1,w1a,w1b) TAP(a2,w0a,w0b)
        ROWLOAD(hb+3*32) TAP(a1,w2a,w2b) TAP(a2,w1a,w1b) TAP(a3,w0a,w0b)
        ROWLOAD(hb+4*32) TAP(a2,w2a,w2b) TAP(a3,w1a,w1b) TAP(a4,w0a,w0b)
        ROWLOAD(hb+5*32) TAP(a3,w2a,w2b) TAP(a4,w1a,w1b) TAP(a5,w0a,w0b)
        ROWLOAD(hb+6*32) TAP(a4,w2a,w2b) TAP(a5,w1a,w1b) TAP(a6,w0a,w0b)
        ROWLOAD(hb+7*32) TAP(a5,w2a,w2b) TAP(a6,w1a,w1b) TAP(a7,w0a,w0b)
        ROWLOAD(hb+8*32) TAP(a6,w2a,w2b) TAP(a7,w1a,w1b)
        ROWLOAD(hb+9*32) TAP(a7,w2a,w2b)
    }
    float s0=hadd(a0),s1=hadd(a1),s2=hadd(a2),s3=hadd(a3);
    float s4=hadd(a4),s5=hadd(a5),s6=hadd(a6),s7=hadd(a7);
    size_t base=(size_t)(b*FF+t0+rbase)*32+co;
    float ssum=0.f, ssq=0.f;
    if (t0+rbase+0<FF){ ssum+=s0; ssq+=s0*s0; c[base+0*32]=s0; }
    if (t0+rbase+1<FF){ ssum+=s1; ssq+=s1*s1; c[base+1*32]=s1; }
    if (t0+rbase+2<FF){ ssum+=s2; ssq+=s2*s2; c[base+2*32]=s2; }
    if (t0+rbase+3<FF){ ssum+=s3; ssq+=s3*s3; c[base+3*32]=s3; }
    if (t0+rbase+4<FF){ ssum+=s4; ssq+=s4*s4; c[base+4*32]=s4; }
    if (t0+rbase+5<FF){ ssum+=s5; ssq+=s5*s5; c[base+5*32]=s5; }
    if (t0+rbase+6<FF){ ssum+=s6; ssq+=s6*s6; c[base+6*32]=s6; }
    if (t0+rbase+7<FF){ ssum+=s7; ssq+=s7*s7; c[base+7*32]=s7; }
    ps[rq][co]=ssum; pq[rq][co]=ssq;
    __syncthreads();
    if (tid<32){
        float s=0.f;
        #pragma unroll
        for(int q=0;q<8;q++) s+=ps[q][tid];
        partials[blockIdx.x*64+tid]=s;
    } else if (tid<64){
        int cc=tid-32;
        float s=0.f;
        #pragma unroll
        for(int q=0;q<8;q++) s+=pq[q][cc];
        partials[blockIdx.x*64+tid]=s;
    }
}

// ---------------- reduce partials -> stats[64] (sum | sumsq) ----------------
__global__ __launch_bounds__(256) void k_reduce(const float* __restrict__ partials,
        float* __restrict__ stats)
{
    __shared__ float sm[4][64];
    int tid=threadIdx.x, col=tid&63, rq=tid>>6;
    int r0=blockIdx.x*80;
    float s=0.f;
    for (int k=rq;k<80;k+=4) s += partials[(r0+k)*64+col];
    sm[rq][col]=s;
    __syncthreads();
    if (tid<64){
        float v=sm[0][tid]+sm[1][tid]+sm[2][tid]+sm[3][tid];
        atomicAdd(&stats[tid], v);
    }
}

// LayerNorm-over-32-lanes + guarded store, all in registers/shuffles.
#define LN_STORE(Y,K) { \
    float s=(Y); \
    s+=__shfl_xor(s,1); s+=__shfl_xor(s,2); s+=__shfl_xor(s,4); \
    s+=__shfl_xor(s,8); s+=__shfl_xor(s,16); \
    float m=s*(1.0f/32.0f); \
    float dd=(Y)-m; float v=dd*dd; \
    v+=__shfl_xor(v,1); v+=__shfl_xor(v,2); v+=__shfl_xor(v,4); \
    v+=__shfl_xor(v,8); v+=__shfl_xor(v,16); \
    float rsd=rsqrtf(v*(1.0f/32.0f)+1e-5f); \
    if (t0+rbase+(K)<FF) hn[(size_t)(b*FF+t0+rbase+(K))*32+co]=dd*rsd*lgv+lbv; }

#define QKV_ROW(ROWOFF, Q, K, V) { \
    float4 t_=*(const float4*)(hb+(ROWOFF)*32); \
    v2f hp_=mk2(t_.x,t_.y), hq_=mk2(t_.z,t_.w); \
    Q=pkfma(hp_,wqa,Q); Q=pkfma(hq_,wqb,Q); \
    K=pkfma(hp_,wka,K); K=pkfma(hq_,wkb,K); \
    V=pkfma(hp_,wva,V); V=pkfma(hq_,wvb,V); }

// ---------------- fused layer: qkv + BN/gelu(conv) + attn + proj + LN ----------------
// cv == hn: conv value (r,co) read strictly before phase E overwrites it;
// blocks own disjoint row ranges.
__global__ __launch_bounds__(256) void k_layer(const float* __restrict__ h,
        float* __restrict__ hn, const float* __restrict__ cv,
        const float* __restrict__ stats,
        const float* __restrict__ bn_g, const float* __restrict__ bn_b,
        const float* __restrict__ qkv_w, const float* __restrict__ proj_w,
        const float* __restrict__ proj_b, const float* __restrict__ ln_g,
        const float* __restrict__ ln_b, int layer)
{
    __shared__ float hs[66*32];            // rows f = t0 .. t0+65
    __shared__ float qs[66*SQ];            // becomes attn output in-place
    __shared__ float ks[66*SQ];
    __shared__ float vs[66*SQ];

    int b=blockIdx.x/NT, t=blockIdx.x%NT, t0=t*TILE, tid=threadIdx.x;
    for (int i4=tid;i4<66*8;i4+=256){
        int r=i4>>3, f=t0+r;
        float4 v=make_float4(0.f,0.f,0.f,0.f);
        if (f<FF) v=*(const float4*)(h+(size_t)(b*FF+f)*32+(i4&7)*4);
        *(float4*)&hs[r*32+(i4&7)*4]=v;
    }
    __syncthreads();

    int co=tid&31, rq=tid>>5, rbase=rq*8;
    float y0,y1,y2,y3,y4,y5,y6,y7;
    {
        float mu  = stats[co]*(1.0f/(float)BF);
        float var = stats[32+co]*(1.0f/(float)BF) - mu*mu;
        float rs  = rsqrtf(fmaxf(var,0.f)+1e-5f);
        float g   = bn_g[layer*32+co];
        float scv = g*rs;
        float shv = bn_b[layer*32+co] - mu*g*rs;
        size_t base=(size_t)(b*FF+t0+rbase)*32+co;
        float c0=(t0+rbase+0<FF)?cv[base+0*32]:0.f;
        float c1=(t0+rbase+1<FF)?cv[base+1*32]:0.f;
        float c2=(t0+rbase+2<FF)?cv[base+2*32]:0.f;
        float c3=(t0+rbase+3<FF)?cv[base+3*32]:0.f;
        float c4v=(t0+rbase+4<FF)?cv[base+4*32]:0.f;
        float c5=(t0+rbase+5<FF)?cv[base+5*32]:0.f;
        float c6=(t0+rbase+6<FF)?cv[base+6*32]:0.f;
        float c7=(t0+rbase+7<FF)?cv[base+7*32]:0.f;
        y0=gelu_exact(fmaf(c0,scv,shv));
        y1=gelu_exact(fmaf(c1,scv,shv));
        y2=gelu_exact(fmaf(c2,scv,shv));
        y3=gelu_exact(fmaf(c3,scv,shv));
        y4=gelu_exact(fmaf(c4v,scv,shv));
        y5=gelu_exact(fmaf(c5,scv,shv));
        y6=gelu_exact(fmaf(c6,scv,shv));
        y7=gelu_exact(fmaf(c7,scv,shv));
    }
    {
        const float* wql = qkv_w + layer*3072 + co;
        v2f q0=mk2(0,0),q1=q0,q2=q0,q3=q0,q4=q0,q5=q0,q6=q0,q7=q0;
        v2f k0=q0,k1=q0,k2=q0,k3=q0,k4=q0,k5=q0,k6=q0,k7=q0;
        v2f v0=q0,v1=q0,v2=q0,v3=q0,v4=q0,v5=q0,v6=q0,v7=q0;
        v2f ek=q0, ev=q0;                    // tid<64: k,v for row 64+rq
        int edge = (tid<64);
        #pragma unroll 1
        for (int c4=0;c4<8;c4++){
            const float* qw=wql+c4*384;      // ci=c4*4, stride 96
            v2f wqa=mk2(qw[0],  qw[96]),  wqb=mk2(qw[192],qw[288]);
            v2f wka=mk2(qw[32], qw[128]), wkb=mk2(qw[224],qw[320]);
            v2f wva=mk2(qw[64], qw[160]), wvb=mk2(qw[256],qw[352]);
            const float* hb=&hs[rbase*32+c4*4];
            QKV_ROW(0,q0,k0,v0)
            QKV_ROW(1,q1,k1,v1)
            QKV_ROW(2,q2,k2,v2)
            QKV_ROW(3,q3,k3,v3)
            QKV_ROW(4,q4,k4,v4)
            QKV_ROW(5,q5,k5,v5)
            QKV_ROW(6,q6,k6,v6)
            QKV_ROW(7,q7,k7,v7)
            if (edge){
                float4 t_=*(const float4*)(&hs[(64+rq)*32+c4*4]);
                v2f hp_=mk2(t_.x,t_.y), hq_=mk2(t_.z,t_.w);
                ek=pkfma(hp_,wka,ek); ek=pkfma(hq_,wkb,ek);
                ev=pkfma(hp_,wva,ev); ev=pkfma(hq_,wvb,ev);
            }
        }
        int rb=rbase*SQ+co;
        qs[rb+0*SQ]=hadd(q0); ks[rb+0*SQ]=hadd(k0); vs[rb+0*SQ]=hadd(v0);
        qs[rb+1*SQ]=hadd(q1); ks[rb+1*SQ]=hadd(k1); vs[rb+1*SQ]=hadd(v1);
        qs[rb+2*SQ]=hadd(q2); ks[rb+2*SQ]=hadd(k2); vs[rb+2*SQ]=hadd(v2);
        qs[rb+3*SQ]=hadd(q3); ks[rb+3*SQ]=hadd(k3); vs[rb+3*SQ]=hadd(v3);
        qs[rb+4*SQ]=hadd(q4); ks[rb+4*SQ]=hadd(k4); vs[rb+4*SQ]=hadd(v4);
        qs[rb+5*SQ]=hadd(q5); ks[rb+5*SQ]=hadd(k5); vs[rb+5*SQ]=hadd(v5);
        qs[rb+6*SQ]=hadd(q6); ks[rb+6*SQ]=hadd(k6); vs[rb+6*SQ]=hadd(v6);
        qs[rb+7*SQ]=hadd(q7); ks[rb+7*SQ]=hadd(k7); vs[rb+7*SQ]=hadd(v7);
        if (edge){ ks[(64+rq)*SQ+co]=hadd(ek); vs[(64+rq)*SQ+co]=hadd(ev); }
    }
    __syncthreads();

    // ---- phase C: banded attention (qs in-place) ----
    {
        int r=tid>>2, hh=tid&3, f=t0+r;
        if (f<FF){
            int base=hh*8;
            float4 qa=*(const float4*)&qs[r*SQ+base];
            float4 qb=*(const float4*)&qs[r*SQ+base+4];
            float s0, s1=-1e30f, s2=-1e30f;
            s0=dot4(qa,*(const float4*)&ks[r*SQ+base],
               dot4(qb,*(const float4*)&ks[r*SQ+base+4],0.f))*0.35355339059327373f;
            if (f+1<FF)
                s1=dot4(qa,*(const float4*)&ks[(r+1)*SQ+base],
                   dot4(qb,*(const float4*)&ks[(r+1)*SQ+base+4],0.f))*0.35355339059327373f;
            if (f+2<FF)
                s2=dot4(qa,*(const float4*)&ks[(r+2)*SQ+base],
                   dot4(qb,*(const float4*)&ks[(r+2)*SQ+base+4],0.f))*0.35355339059327373f;
            float mx=fmaxf(s0,fmaxf(s1,s2));
            float e0=__expf(s0-mx);
            float e1=(f+1<FF)?__expf(s1-mx):0.f;
            float e2=(f+2<FF)?__expf(s2-mx):0.f;
            float inv=1.0f/(e0+e1+e2);
            float4 va=*(const float4*)&vs[r*SQ+base];
            float4 vb=*(const float4*)&vs[r*SQ+base+4];
            float4 oa=make_float4(e0*va.x,e0*va.y,e0*va.z,e0*va.w);
            float4 ob=make_float4(e0*vb.x,e0*vb.y,e0*vb.z,e0*vb.w);
            if (f+1<FF){
                va=*(const float4*)&vs[(r+1)*SQ+base];
                vb=*(const float4*)&vs[(r+1)*SQ+base+4];
                oa.x=fmaf(e1,va.x,oa.x); oa.y=fmaf(e1,va.y,oa.y);
                oa.z=fmaf(e1,va.z,oa.z); oa.w=fmaf(e1,va.w,oa.w);
                ob.x=fmaf(e1,vb.x,ob.x); ob.y=fmaf(e1,vb.y,ob.y);
                ob.z=fmaf(e1,vb.z,ob.z); ob.w=fmaf(e1,vb.w,ob.w);
            }
            if (f+2<FF){
                va=*(const float4*)&vs[(r+2)*SQ+base];
                vb=*(const float4*)&vs[(r+2)*SQ+base+4];
                oa.x=fmaf(e2,va.x,oa.x); oa.y=fmaf(e2,va.y,oa.y);
                oa.z=fmaf(e2,va.z,oa.z); oa.w=fmaf(e2,va.w,oa.w);
                ob.x=fmaf(e2,vb.x,ob.x); ob.y=fmaf(e2,vb.y,ob.y);
                ob.z=fmaf(e2,vb.z,ob.z); ob.w=fmaf(e2,vb.w,ob.w);
            }
            oa.x*=inv; oa.y*=inv; oa.z*=inv; oa.w*=inv;
            ob.x*=inv; ob.y*=inv; ob.z*=inv; ob.w*=inv;
            *(float4*)&qs[r*SQ+base]=oa;
            *(float4*)&qs[r*SQ+base+4]=ob;
        }
    }
    __syncthreads();

    // ---- phase D: proj + residual into y regs ----
    {
        const float* pwl = proj_w + layer*1024 + co;
        float pbv = proj_b[layer*32+co];
        v2f d0=mk2(0,0),d1=d0,d2=d0,d3=d0,d4=d0,d5=d0,d6=d0,d7=d0;
        v2f hp, hq;
        #pragma unroll 1
        for (int c4=0;c4<8;c4++){
            const float* w=pwl+c4*128;
            v2f pwa=mk2(w[0],w[32]), pwb=mk2(w[64],w[96]);
            const float* qb=&qs[rbase*SQ+c4*4];
            ROWLOAD(qb+0*SQ) TAP(d0,pwa,pwb)
            ROWLOAD(qb+1*SQ) TAP(d1,pwa,pwb)
            ROWLOAD(qb+2*SQ) TAP(d2,pwa,pwb)
            ROWLOAD(qb+3*SQ) TAP(d3,pwa,pwb)
            ROWLOAD(qb+4*SQ) TAP(d4,pwa,pwb)
            ROWLOAD(qb+5*SQ) TAP(d5,pwa,pwb)
            ROWLOAD(qb+6*SQ) TAP(d6,pwa,pwb)
            ROWLOAD(qb+7*SQ) TAP(d7,pwa,pwb)
        }
        y0+=pbv+hadd(d0); y1+=pbv+hadd(d1); y2+=pbv+hadd(d2); y3+=pbv+hadd(d3);
        y4+=pbv+hadd(d4); y5+=pbv+hadd(d5); y6+=pbv+hadd(d6); y7+=pbv+hadd(d7);
    }

    // ---- phase E: LayerNorm via lane shuffles + fused store ----
    {
        float lgv=ln_g[layer*32+co];
        float lbv=ln_b[layer*32+co];
        LN_STORE(y0,0) LN_STORE(y1,1) LN_STORE(y2,2) LN_STORE(y3,3)
        LN_STORE(y4,4) LN_STORE(y5,5) LN_STORE(y6,6) LN_STORE(y7,7)
    }
}

// ---------------- head: sigmoid(gelu(h@h1+b1)@h2+b2) ----------------
__global__ __launch_bounds__(256) void k_head(const float* __restrict__ h,
        const float* __restrict__ h1_w, const float* __restrict__ h1_b,
        const float* __restrict__ h2_w, const float* __restrict__ h2_b,
        float* __restrict__ out)
{
    __shared__ float hs[256*SQ];
    __shared__ float w1t[16*32];     // transposed h1_w
    int tid=threadIdx.x;
    int r0=blockIdx.x*256;           // BF == 1028*256 exactly
    for (int i4=tid;i4<256*8;i4+=256){
        float4 v=*(const float4*)(h+(size_t)r0*32+i4*4);
        *(float4*)&hs[(i4>>3)*SQ+(i4&7)*4]=v;
    }
    for (int i=tid;i<512;i+=256) w1t[i]=h1_w[(i&31)*16+(i>>5)];
    __syncthreads();
    float4 t0v=*(const float4*)&hs[tid*SQ+ 0];
    float4 t1v=*(const float4*)&hs[tid*SQ+ 4];
    float4 t2v=*(const float4*)&hs[tid*SQ+ 8];
    float4 t3v=*(const float4*)&hs[tid*SQ+12];
    float4 t4v=*(const float4*)&hs[tid*SQ+16];
    float4 t5v=*(const float4*)&hs[tid*SQ+20];
    float4 t6v=*(const float4*)&hs[tid*SQ+24];
    float4 t7v=*(const float4*)&hs[tid*SQ+28];
    v2f h0a=mk2(t0v.x,t0v.y), h0b=mk2(t0v.z,t0v.w);
    v2f h1a=mk2(t1v.x,t1v.y), h1b=mk2(t1v.z,t1v.w);
    v2f h2a=mk2(t2v.x,t2v.y), h2b=mk2(t2v.z,t2v.w);
    v2f h3a=mk2(t3v.x,t3v.y), h3b=mk2(t3v.z,t3v.w);
    v2f h4a=mk2(t4v.x,t4v.y), h4b=mk2(t4v.z,t4v.w);
    v2f h5a=mk2(t5v.x,t5v.y), h5b=mk2(t5v.z,t5v.w);
    v2f h6a=mk2(t6v.x,t6v.y), h6b=mk2(t6v.z,t6v.w);
    v2f h7a=mk2(t7v.x,t7v.y), h7b=mk2(t7v.z,t7v.w);
    float acc2=h2_b[0];
    #pragma unroll
    for (int j=0;j<16;j++){
        const float* wr=&w1t[j*32];
        float4 wv0=*(const float4*)(wr+ 0);
        float4 wv1=*(const float4*)(wr+ 4);
        float4 wv2=*(const float4*)(wr+ 8);
        float4 wv3=*(const float4*)(wr+12);
        float4 wv4=*(const float4*)(wr+16);
        float4 wv5=*(const float4*)(wr+20);
        float4 wv6=*(const float4*)(wr+24);
        float4 wv7=*(const float4*)(wr+28);
        v2f aj=mk2(0,0);
        aj=pkfma(h0a,mk2(wv0.x,wv0.y),aj); aj=pkfma(h0b,mk2(wv0.z,wv0.w),aj);
        aj=pkfma(h1a,mk2(wv1.x,wv1.y),aj); aj=pkfma(h1b,mk2(wv1.z,wv1.w),aj);
        aj=pkfma(h2a,mk2(wv2.x,wv2.y),aj); aj=pkfma(h2b,mk2(wv2.z,wv2.w),aj);
        aj=pkfma(h3a,mk2(wv3.x,wv3.y),aj); aj=pkfma(h3b,mk2(wv3.z,wv3.w),aj);
        aj=pkfma(h4a,mk2(wv4.x,wv4.y),aj); aj=pkfma(h4b,mk2(wv4.z,wv4.w),aj);
        aj=pkfma(h5a,mk2(wv5.x,wv5.y),aj); aj=pkfma(h5b,mk2(wv5.z,wv5.w),aj);
        aj=pkfma(h6a,mk2(wv6.x,wv6.y),aj); aj=pkfma(h6b,mk2(wv6.z,wv6.w),aj);
        aj=pkfma(h7a,mk2(wv7.x,wv7.y),aj); aj=pkfma(h7b,mk2(wv7.z,wv7.w),aj);
        acc2=fmaf(gelu_exact(h1_b[j]+hadd(aj)), h2_w[j], acc2);
    }
    out[r0+tid]=1.0f/(1.0f+__expf(-acc2));
}

extern "C" void kernel_launch(void* const* d_in, const int* in_sizes, int n_in,
                              void* d_out, int out_size, void* d_ws, size_t ws_size,
                              hipStream_t stream)
{
    const float* x     =(const float*)d_in[0];
    const float* in_w  =(const float*)d_in[1];
    const float* in_b  =(const float*)d_in[2];
    const float* conv_w=(const float*)d_in[3];
    const float* bn_g  =(const float*)d_in[4];
    const float* bn_b  =(const float*)d_in[5];
    const float* qkv_w =(const float*)d_in[6];
    const float* proj_w=(const float*)d_in[7];
    const float* proj_b=(const float*)d_in[8];
    const float* ln_g  =(const float*)d_in[9];
    const float* ln_b  =(const float*)d_in[10];
    const float* h1_w  =(const float*)d_in[11];
    const float* h1_b  =(const float*)d_in[12];
    const float* h2_w  =(const float*)d_in[13];
    const float* h2_b  =(const float*)d_in[14];

    float* bufA     = (float*)d_ws;
    float* bufB     = bufA + (size_t)BF*32;
    float* partials = bufB + (size_t)BF*32;
    float* stats    = partials + (size_t)NBLK*64;

    k_zero<<<1,256,0,stream>>>(stats);
    k_inproj<<<NBLK,256,0,stream>>>(x,in_w,in_b,bufA);
    for (int l=0;l<NLAYER;l++){
        float* cur = (l&1)? bufB : bufA;
        float* nxt = (l&1)? bufA : bufB;
        k_conv<<<NBLK,256,0,stream>>>(cur, conv_w, l, nxt, partials);
        k_reduce<<<64,256,0,stream>>>(partials, stats + l*64);
        k_layer<<<NBLK,256,0,stream>>>(cur, nxt, nxt, stats+l*64, bn_g, bn_b,
                                       qkv_w, proj_w, proj_b, ln_g, ln_b, l);
    }
    k_head<<<1028,256,0,stream>>>(bufA, h1_w,h1_b,h2_w,h2_b, (float*)d_out);
}